// Round 20
// baseline (65.151 us; speedup 1.0000x reference)
//
#include <hip/hip_runtime.h>
#include <hip/hip_fp16.h>

#define NN 3072
#define F 256
#define NH 8
#define ALPHA 0.2f
#define LN_EPS 1e-5f
#define LOG2E 1.44269504f

typedef float f32x4 __attribute__((ext_vector_type(4)));
typedef _Float16 f16x8 __attribute__((ext_vector_type(8)));

// ============ Kernel A: h = x @ W^T via MFMA (f16 in, f32 acc) ============
__global__ __launch_bounds__(256) void gemm_h_mfma(const float* __restrict__ x,
                                                   const float* __restrict__ W,
                                                   const float* __restrict__ asrc_w,
                                                   const float* __restrict__ adst_w,
                                                   _Float16* __restrict__ hblk,
                                                   float* __restrict__ a_src,
                                                   float* __restrict__ a_dstT) {
  __shared__ _Float16 ys[16][136];
  const int t = threadIdx.x, w = t >> 6, l = t & 63;
  const int col = l & 15, kg = l >> 4;
  const int it = blockIdx.x >> 1, half = blockIdx.x & 1;
  const int i0 = it * 16;
  const int cbase = half * 128 + w * 32 + col;  // wave's head = half*4 + w
  f32x4 acc0 = {0.f, 0.f, 0.f, 0.f}, acc1 = acc0;
  const float* xrow = x + (size_t)(i0 + col) * F + kg * 8;
  const float* wr0 = W + (size_t)cbase * F + kg * 8;
  const float* wr1 = wr0 + (size_t)16 * F;
  for (int ks = 0; ks < 8; ++ks) {
    const int k0 = ks * 32;
    f16x8 af, bf0, bf1;
    {
      const f32x4 a = *(const f32x4*)(xrow + k0);
      const f32x4 b = *(const f32x4*)(xrow + k0 + 4);
#pragma unroll
      for (int e = 0; e < 4; ++e) { af[e] = (_Float16)a[e]; af[4 + e] = (_Float16)b[e]; }
    }
#define LDB(dst, ptr)                                                     \
    {                                                                     \
      const f32x4 a = *(const f32x4*)((ptr) + k0);                        \
      const f32x4 b = *(const f32x4*)((ptr) + k0 + 4);                    \
      _Pragma("unroll")                                                   \
      for (int e = 0; e < 4; ++e) { dst[e] = (_Float16)a[e]; dst[4 + e] = (_Float16)b[e]; } \
    }
    LDB(bf0, wr0) LDB(bf1, wr1)
#undef LDB
    acc0 = __builtin_amdgcn_mfma_f32_16x16x32_f16(af, bf0, acc0, 0, 0, 0);
    acc1 = __builtin_amdgcn_mfma_f32_16x16x32_f16(af, bf1, acc1, 0, 0, 0);
  }
  const int hh = half * 4 + w;
  const float ws0 = asrc_w[cbase], ws1 = asrc_w[cbase + 16];
  const float wd0 = adst_w[cbase], wd1 = adst_w[cbase + 16];
#pragma unroll
  for (int r = 0; r < 4; ++r) {
    float p = acc0[r] * ws0 + acc1[r] * ws1;
    float q = acc0[r] * wd0 + acc1[r] * wd1;
#pragma unroll
    for (int off = 1; off < 16; off <<= 1) {
      p += __shfl_xor(p, off);
      q += __shfl_xor(q, off);
    }
    if (col == 0) {
      const int row = i0 + kg * 4 + r;
      a_src[(size_t)row * NH + hh] = p;
      a_dstT[(size_t)hh * NN + row] = q * LOG2E;  // pre-scaled for exp2
    }
  }
#pragma unroll
  for (int r = 0; r < 4; ++r) {
    ys[kg * 4 + r][w * 32 + col] = (_Float16)acc0[r];
    ys[kg * 4 + r][w * 32 + 16 + col] = (_Float16)acc1[r];
  }
  __syncthreads();
  const int dl = t >> 1, jset = (t & 1) * 8;
  const int jb = i0 >> 5, jjb = (i0 & 31) + jset;
  f16x8 hv;
#pragma unroll
  for (int q = 0; q < 8; ++q) hv[q] = ys[jset + q][dl];
  *(f16x8*)(hblk + (size_t)jb * (F * 32) + (half * 128 + dl) * 32 + jjb) = hv;
}

// ============ Kernel C: dense GAT aggregation via MFMA, LDS-staged ============
// Cooperative double-buffered LDS staging (R19 structure). NEW: staging
// buffers (6.1 KB, live during loop) OVERLAID with opart (17.4 KB, live
// after loop) — lifetimes separated by the loop's final __syncthreads.
// LDS 23.5 -> 17.4 KB => more blocks/CU resident.
template <int KCn>
__global__ __launch_bounds__(256) void gat_mfma(const float* __restrict__ adj,
                                                const _Float16* __restrict__ hblk,
                                                const float* __restrict__ a_src,
                                                const float* __restrict__ a_dstT,
                                                const float* __restrict__ edge_W,
                                                const float* __restrict__ edge_b,
                                                _Float16* __restrict__ part,
                                                float* __restrict__ swp) {
  __shared__ __align__(16) float smem_u[4 * 16 * 68];          // 17408 B
  float (*opart)[16][68] = (float (*)[16][68])smem_u;          // post-loop
  float (*adj_s)[16][32] = (float (*)[16][32])smem_u;          // loop: 4096 B
  float (*adT_s)[8][32] = (float (*)[8][32])(smem_u + 1024);   // loop: 2048 B
  const int bid = blockIdx.x;
  const int i0 = (bid % 192) * 16;
  const int kc = bid / 192;
  const int t = threadIdx.x, w = t >> 6, lane = t & 63;
  const int col = lane & 15, kg = lane >> 4;
  const int h0 = w * 2, h1 = h0 + 1, d0 = w * 64;
  const float ew0 = edge_W[h0] * LOG2E, ew1 = edge_W[h1] * LOG2E;
  const float base0 = (a_src[(size_t)(i0 + col) * NH + h0] + edge_b[h0]) * LOG2E;
  const float base1 = (a_src[(size_t)(i0 + col) * NH + h1] + edge_b[h1]) * LOG2E;
  const int kg8 = kg * 8;
  // swizzled chunk indices for this lane's adjacency reads (row = col)
  const int c0_ = ((kg * 2) ^ (col & 7)) * 4;
  const int c1_ = ((kg * 2 + 1) ^ (col & 7)) * 4;
  // staging role constants
  const int srow = (w << 3) + (lane >> 3);  // w<2: adjacency row 0..15
  const int lch = lane & 7;                 // logical 4-float chunk
  const int pch = lch ^ (srow & 7);         // swizzled physical chunk (adj)

  f32x4 acc00 = {0.f, 0.f, 0.f, 0.f}, acc01 = acc00, acc10 = acc00, acc11 = acc00;
  f32x4 accs0 = acc00, accs1 = acc00;
  const f16x8 ones = {(_Float16)1, (_Float16)1, (_Float16)1, (_Float16)1,
                      (_Float16)1, (_Float16)1, (_Float16)1, (_Float16)1};
  constexpr int KCL = NN / KCn;
  constexpr int NSTEP = KCL / 32;
  const int jc0 = kc * KCL;

  f32x4 stg = {0.f, 0.f, 0.f, 0.f};
#define STAGE_LOAD(jv)                                                         \
  {                                                                            \
    if (w < 2)                                                                 \
      stg = *(const f32x4*)(adj + (size_t)(i0 + srow) * NN + (jv) + lch * 4);  \
    else if (w == 2)                                                           \
      stg = *(const f32x4*)(a_dstT + (size_t)(lane >> 3) * NN + (jv) + lch * 4); \
  }
#define STAGE_WRITE(nb)                                                        \
  {                                                                            \
    if (w < 2)                                                                 \
      *(f32x4*)&adj_s[nb][srow][pch * 4] = stg;                                \
    else if (w == 2)                                                           \
      *(f32x4*)&adT_s[nb][lane >> 3][lch * 4] = stg;                           \
  }
#define KCOMP(cur, jbv)                                                        \
  {                                                                            \
    const _Float16* bp = hblk + (size_t)((jbv) >> 5) * (F * 32) + kg8;         \
    const f16x8 b00 = *(const f16x8*)(bp + (d0 + col) * 32);                   \
    const f16x8 b01 = *(const f16x8*)(bp + (d0 + 16 + col) * 32);              \
    const f16x8 b10 = *(const f16x8*)(bp + (d0 + 32 + col) * 32);              \
    const f16x8 b11 = *(const f16x8*)(bp + (d0 + 48 + col) * 32);              \
    const f32x4 av0 = *(const f32x4*)&adj_s[cur][col][c0_];                    \
    const f32x4 av1 = *(const f32x4*)&adj_s[cur][col][c1_];                    \
    const f32x4 dv00 = *(const f32x4*)&adT_s[cur][h0][kg8];                    \
    const f32x4 dv01 = *(const f32x4*)&adT_s[cur][h0][kg8 + 4];                \
    const f32x4 dv10 = *(const f32x4*)&adT_s[cur][h1][kg8];                    \
    const f32x4 dv11 = *(const f32x4*)&adT_s[cur][h1][kg8 + 4];                \
    f16x8 a0, a1;                                                              \
    _Pragma("unroll")                                                          \
    for (int e = 0; e < 8; ++e) {                                              \
      const float av = (e < 4) ? av0[e & 3] : av1[e & 3];                      \
      const float dv0 = (e < 4) ? dv00[e & 3] : dv01[e & 3];                   \
      const float dv1 = (e < 4) ? dv10[e & 3] : dv11[e & 3];                   \
      float l0 = fmaf(av, ew0, base0 + dv0);                                   \
      l0 = fmaxf(l0, ALPHA * l0);                                              \
      const float w0_ = (av > 0.f) ? __builtin_amdgcn_exp2f(l0) : 0.f;         \
      a0[e] = (_Float16)w0_;                                                   \
      float l1 = fmaf(av, ew1, base1 + dv1);                                   \
      l1 = fmaxf(l1, ALPHA * l1);                                              \
      const float w1_ = (av > 0.f) ? __builtin_amdgcn_exp2f(l1) : 0.f;         \
      a1[e] = (_Float16)w1_;                                                   \
    }                                                                          \
    acc00 = __builtin_amdgcn_mfma_f32_16x16x32_f16(a0, b00, acc00, 0, 0, 0);   \
    acc01 = __builtin_amdgcn_mfma_f32_16x16x32_f16(a0, b01, acc01, 0, 0, 0);   \
    accs0 = __builtin_amdgcn_mfma_f32_16x16x32_f16(a0, ones, accs0, 0, 0, 0);  \
    acc10 = __builtin_amdgcn_mfma_f32_16x16x32_f16(a1, b10, acc10, 0, 0, 0);   \
    acc11 = __builtin_amdgcn_mfma_f32_16x16x32_f16(a1, b11, acc11, 0, 0, 0);   \
    accs1 = __builtin_amdgcn_mfma_f32_16x16x32_f16(a1, ones, accs1, 0, 0, 0);  \
  }

  // prologue: stage step 0
  int jn = jc0;
  STAGE_LOAD(jn);
  STAGE_WRITE(0);
  __syncthreads();
  for (int s = 0; s < NSTEP; ++s) {
    const int cur = s & 1;
    const bool more = (s + 1 < NSTEP);
    if (more) STAGE_LOAD(jn + 32);   // issue early: hides under KCOMP
    KCOMP(cur, jn);
    if (more) STAGE_WRITE(cur ^ 1);  // write late
    __syncthreads();                 // also fences staging-buf lifetime
    jn += 32;
  }
#undef STAGE_LOAD
#undef STAGE_WRITE
#undef KCOMP

  // denominators from ones-MFMA accumulators (rows kg*4+r; take col 0)
  if (col == 0) {
#pragma unroll
    for (int r = 0; r < 4; ++r) {
      swp[((size_t)kc * NN + i0 + kg * 4 + r) * NH + h0] = accs0[r];
      swp[((size_t)kc * NN + i0 + kg * 4 + r) * NH + h1] = accs1[r];
    }
  }
  // stage accs (overlaid region — staging bufs dead past final barrier),
  // wave-private transpose, packed f16 stores
#pragma unroll
  for (int r = 0; r < 4; ++r) {
    opart[w][kg * 4 + r][col] = acc00[r];
    opart[w][kg * 4 + r][16 + col] = acc01[r];
    opart[w][kg * 4 + r][32 + col] = acc10[r];
    opart[w][kg * 4 + r][48 + col] = acc11[r];
  }
  const int rr = col, cg = kg;
  f16x8 o0, o1;
#pragma unroll
  for (int q = 0; q < 8; ++q) {
    o0[q] = (_Float16)opart[w][rr][cg * 16 + q];
    o1[q] = (_Float16)opart[w][rr][cg * 16 + 8 + q];
  }
  _Float16* pdst = part + ((size_t)kc * NN + i0 + rr) * F + d0 + cg * 16;
  *(f16x8*)(pdst) = o0;
  *(f16x8*)(pdst + 8) = o1;
}

// ============ Kernel D: reduce partials + normalize + MFMA GEMM + LN + ReLU ====
// Grid 384 (8-row i-tiles): xs rows 8..15 zero-padded (zero A-rows -> zero
// output rows, discarded at store) — doubles resident blocks vs 192 grid.
template <int KCn>
__global__ __launch_bounds__(256) void fuse_ln_mfma(const _Float16* __restrict__ part,
                                                    const float* __restrict__ swp,
                                                    const float* __restrict__ fW,
                                                    const float* __restrict__ fb,
                                                    const float* __restrict__ ln_g,
                                                    const float* __restrict__ ln_b,
                                                    float* __restrict__ out) {
  __shared__ _Float16 xs[16][264];
  __shared__ float ssum[8][NH];
  __shared__ float red[2][4][16];
  const int t = threadIdx.x, w = t >> 6, l = t & 63;
  const int col = l & 15, kg = l >> 4;
  const int i0 = blockIdx.x * 8;
  if (t < 64) {
    const int r = t >> 3, hh = t & 7;
    float s = 0.f;
#pragma unroll
    for (int p = 0; p < KCn; ++p) s += swp[((size_t)p * NN + i0 + r) * NH + hh];
    ssum[r][hh] = s;
  }
  __syncthreads();
  {
    const int c8 = (t & 31) * 8;
    const int hh = (t & 31) >> 2;
    const int rr = t >> 5;  // 0..7
    float sm8[8];
#pragma unroll
    for (int q = 0; q < 8; ++q) sm8[q] = 0.f;
#pragma unroll
    for (int p = 0; p < KCn; ++p) {
      const f16x8 v = *(const f16x8*)(part + ((size_t)p * NN + i0 + rr) * F + c8);
#pragma unroll
      for (int q = 0; q < 8; ++q) sm8[q] += (float)v[q];
    }
    const float inv = 1.f / ssum[rr][hh];
    f16x8 xv, zv;
#pragma unroll
    for (int q = 0; q < 8; ++q) { xv[q] = (_Float16)(sm8[q] * inv); zv[q] = (_Float16)0; }
    *(f16x8*)&xs[rr][c8] = xv;
    *(f16x8*)&xs[rr + 8][c8] = zv;  // zero-pad rows 8..15
  }
  __syncthreads();
  const int cbase = w * 64 + col;
  f32x4 acc0 = {0.f, 0.f, 0.f, 0.f}, acc1 = acc0, acc2 = acc0, acc3 = acc0;
  const float* wr0 = fW + (size_t)cbase * F + kg * 8;
  const float* wr1 = wr0 + (size_t)16 * F;
  const float* wr2 = wr0 + (size_t)32 * F;
  const float* wr3 = wr0 + (size_t)48 * F;
  for (int ks = 0; ks < 8; ++ks) {
    const int k0 = ks * 32;
    const f16x8 af = *(const f16x8*)&xs[col][k0 + kg * 8];
    f16x8 bf0, bf1, bf2, bf3;
#define LDB(dst, ptr)                                                     \
    {                                                                     \
      const f32x4 a = *(const f32x4*)((ptr) + k0);                        \
      const f32x4 b = *(const f32x4*)((ptr) + k0 + 4);                    \
      _Pragma("unroll")                                                   \
      for (int e = 0; e < 4; ++e) { dst[e] = (_Float16)a[e]; dst[4 + e] = (_Float16)b[e]; } \
    }
    LDB(bf0, wr0) LDB(bf1, wr1) LDB(bf2, wr2) LDB(bf3, wr3)
#undef LDB
    acc0 = __builtin_amdgcn_mfma_f32_16x16x32_f16(af, bf0, acc0, 0, 0, 0);
    acc1 = __builtin_amdgcn_mfma_f32_16x16x32_f16(af, bf1, acc1, 0, 0, 0);
    acc2 = __builtin_amdgcn_mfma_f32_16x16x32_f16(af, bf2, acc2, 0, 0, 0);
    acc3 = __builtin_amdgcn_mfma_f32_16x16x32_f16(af, bf3, acc3, 0, 0, 0);
  }
  const float fb0 = fb[cbase], fb1 = fb[cbase + 16], fb2 = fb[cbase + 32], fb3 = fb[cbase + 48];
#pragma unroll
  for (int r = 0; r < 4; ++r) {
    acc0[r] += fb0; acc1[r] += fb1; acc2[r] += fb2; acc3[r] += fb3;
  }
  float sm[4], sq[4];
#pragma unroll
  for (int r = 0; r < 4; ++r) {
    sm[r] = acc0[r] + acc1[r] + acc2[r] + acc3[r];
    sq[r] = acc0[r] * acc0[r] + acc1[r] * acc1[r] + acc2[r] * acc2[r] + acc3[r] * acc3[r];
#pragma unroll
    for (int off = 1; off < 16; off <<= 1) {
      sm[r] += __shfl_xor(sm[r], off);
      sq[r] += __shfl_xor(sq[r], off);
    }
  }
  if (col == 0) {
#pragma unroll
    for (int r = 0; r < 4; ++r) {
      red[0][w][kg * 4 + r] = sm[r];
      red[1][w][kg * 4 + r] = sq[r];
    }
  }
  __syncthreads();
  const float g0 = ln_g[cbase], g1 = ln_g[cbase + 16], g2 = ln_g[cbase + 32], g3 = ln_g[cbase + 48];
  const float b0 = ln_b[cbase], b1 = ln_b[cbase + 16], b2 = ln_b[cbase + 32], b3 = ln_b[cbase + 48];
#pragma unroll
  for (int r = 0; r < 4; ++r) {
    const int row = kg * 4 + r;
    if (row < 8) {
      const float S = red[0][0][row] + red[0][1][row] + red[0][2][row] + red[0][3][row];
      const float Q = red[1][0][row] + red[1][1][row] + red[1][2][row] + red[1][3][row];
      const float mu = S * (1.f / F);
      const float rs = rsqrtf(Q * (1.f / F) - mu * mu + LN_EPS);
      float* orow = out + (size_t)(i0 + row) * F;
      orow[cbase] = fmaxf((acc0[r] - mu) * rs * g0 + b0, 0.f);
      orow[cbase + 16] = fmaxf((acc1[r] - mu) * rs * g1 + b1, 0.f);
      orow[cbase + 32] = fmaxf((acc2[r] - mu) * rs * g2 + b2, 0.f);
      orow[cbase + 48] = fmaxf((acc3[r] - mu) * rs * g3 + b3, 0.f);
    }
  }
}

extern "C" void kernel_launch(void* const* d_in, const int* in_sizes, int n_in,
                              void* d_out, int out_size, void* d_ws, size_t ws_size,
                              hipStream_t stream) {
  const float* x = (const float*)d_in[0];
  const float* adj = (const float*)d_in[1];
  const float* W = (const float*)d_in[2];
  const float* attn_src = (const float*)d_in[3];
  const float* attn_dst = (const float*)d_in[4];
  const float* edge_W = (const float*)d_in[5];
  const float* edge_b = (const float*)d_in[6];
  const float* fuse_W = (const float*)d_in[7];
  const float* fuse_b = (const float*)d_in[8];
  const float* ln_g = (const float*)d_in[9];
  const float* ln_b = (const float*)d_in[10];
  float* out = (float*)d_out;

  const int kcn = 8;

  char* p = (char*)d_ws;
  _Float16* hblk = (_Float16*)p;  p += (size_t)NN * F * 2;
  float* a_src = (float*)p;       p += (size_t)NN * NH * 4;
  float* a_dstT = (float*)p;      p += (size_t)NN * NH * 4;
  float* swp = (float*)p;         p += (size_t)kcn * NN * NH * 4;
  _Float16* part = (_Float16*)p;

  gemm_h_mfma<<<384, 256, 0, stream>>>(x, W, attn_src, attn_dst, hblk, a_src, a_dstT);
  gat_mfma<8><<<192 * 8, 256, 0, stream>>>(adj, hblk, a_src, a_dstT, edge_W, edge_b, part, swp);
  fuse_ln_mfma<8><<<NN / 8, 256, 0, stream>>>(part, swp, fuse_W, fuse_b, ln_g, ln_b, out);
}

// Round 21
// 64.185 us; speedup vs baseline: 1.0151x; 1.0151x over previous
//
#include <hip/hip_runtime.h>
#include <hip/hip_fp16.h>

#define NN 3072
#define F 256
#define NH 8
#define ALPHA 0.2f
#define LN_EPS 1e-5f
#define LOG2E 1.44269504f

typedef float f32x4 __attribute__((ext_vector_type(4)));
typedef _Float16 f16x8 __attribute__((ext_vector_type(8)));

// ============ Kernel A: h = x @ W^T via MFMA (f16 in, f32 acc) ============
__global__ __launch_bounds__(256) void gemm_h_mfma(const float* __restrict__ x,
                                                   const float* __restrict__ W,
                                                   const float* __restrict__ asrc_w,
                                                   const float* __restrict__ adst_w,
                                                   _Float16* __restrict__ hblk,
                                                   float* __restrict__ a_src,
                                                   float* __restrict__ a_dstT) {
  __shared__ _Float16 ys[16][136];
  const int t = threadIdx.x, w = t >> 6, l = t & 63;
  const int col = l & 15, kg = l >> 4;
  const int it = blockIdx.x >> 1, half = blockIdx.x & 1;
  const int i0 = it * 16;
  const int cbase = half * 128 + w * 32 + col;  // wave's head = half*4 + w
  f32x4 acc0 = {0.f, 0.f, 0.f, 0.f}, acc1 = acc0;
  const float* xrow = x + (size_t)(i0 + col) * F + kg * 8;
  const float* wr0 = W + (size_t)cbase * F + kg * 8;
  const float* wr1 = wr0 + (size_t)16 * F;
  for (int ks = 0; ks < 8; ++ks) {
    const int k0 = ks * 32;
    f16x8 af, bf0, bf1;
    {
      const f32x4 a = *(const f32x4*)(xrow + k0);
      const f32x4 b = *(const f32x4*)(xrow + k0 + 4);
#pragma unroll
      for (int e = 0; e < 4; ++e) { af[e] = (_Float16)a[e]; af[4 + e] = (_Float16)b[e]; }
    }
#define LDB(dst, ptr)                                                     \
    {                                                                     \
      const f32x4 a = *(const f32x4*)((ptr) + k0);                        \
      const f32x4 b = *(const f32x4*)((ptr) + k0 + 4);                    \
      _Pragma("unroll")                                                   \
      for (int e = 0; e < 4; ++e) { dst[e] = (_Float16)a[e]; dst[4 + e] = (_Float16)b[e]; } \
    }
    LDB(bf0, wr0) LDB(bf1, wr1)
#undef LDB
    acc0 = __builtin_amdgcn_mfma_f32_16x16x32_f16(af, bf0, acc0, 0, 0, 0);
    acc1 = __builtin_amdgcn_mfma_f32_16x16x32_f16(af, bf1, acc1, 0, 0, 0);
  }
  const int hh = half * 4 + w;
  const float ws0 = asrc_w[cbase], ws1 = asrc_w[cbase + 16];
  const float wd0 = adst_w[cbase], wd1 = adst_w[cbase + 16];
#pragma unroll
  for (int r = 0; r < 4; ++r) {
    float p = acc0[r] * ws0 + acc1[r] * ws1;
    float q = acc0[r] * wd0 + acc1[r] * wd1;
#pragma unroll
    for (int off = 1; off < 16; off <<= 1) {
      p += __shfl_xor(p, off);
      q += __shfl_xor(q, off);
    }
    if (col == 0) {
      const int row = i0 + kg * 4 + r;
      a_src[(size_t)row * NH + hh] = p;
      a_dstT[(size_t)hh * NN + row] = q * LOG2E;  // pre-scaled for exp2
    }
  }
#pragma unroll
  for (int r = 0; r < 4; ++r) {
    ys[kg * 4 + r][w * 32 + col] = (_Float16)acc0[r];
    ys[kg * 4 + r][w * 32 + 16 + col] = (_Float16)acc1[r];
  }
  __syncthreads();
  const int dl = t >> 1, jset = (t & 1) * 8;
  const int jb = i0 >> 5, jjb = (i0 & 31) + jset;
  f16x8 hv;
#pragma unroll
  for (int q = 0; q < 8; ++q) hv[q] = ys[jset + q][dl];
  *(f16x8*)(hblk + (size_t)jb * (F * 32) + (half * 128 + dl) * 32 + jjb) = hv;
}

// ============ Kernel C: dense GAT aggregation via MFMA, LDS-staged ============
// EXACT R19 kernel (57.5 us total): separate __shared__ staging buffers
// (alias-analyzable — R20's casted overlay regressed), double-buffered
// cooperative staging, ones-MFMA denominators, HW exp2.
template <int KCn>
__global__ __launch_bounds__(256) void gat_mfma(const float* __restrict__ adj,
                                                const _Float16* __restrict__ hblk,
                                                const float* __restrict__ a_src,
                                                const float* __restrict__ a_dstT,
                                                const float* __restrict__ edge_W,
                                                const float* __restrict__ edge_b,
                                                _Float16* __restrict__ part,
                                                float* __restrict__ swp) {
  __shared__ float opart[4][16][68];
  __shared__ float adj_s[2][16][32];  // [buf][row][j], chunk-swizzled
  __shared__ float adT_s[2][8][32];   // [buf][head][j]
  const int bid = blockIdx.x;
  const int i0 = (bid % 192) * 16;
  const int kc = bid / 192;
  const int t = threadIdx.x, w = t >> 6, lane = t & 63;
  const int col = lane & 15, kg = lane >> 4;
  const int h0 = w * 2, h1 = h0 + 1, d0 = w * 64;
  const float ew0 = edge_W[h0] * LOG2E, ew1 = edge_W[h1] * LOG2E;
  const float base0 = (a_src[(size_t)(i0 + col) * NH + h0] + edge_b[h0]) * LOG2E;
  const float base1 = (a_src[(size_t)(i0 + col) * NH + h1] + edge_b[h1]) * LOG2E;
  const int kg8 = kg * 8;
  const int c0_ = ((kg * 2) ^ (col & 7)) * 4;
  const int c1_ = ((kg * 2 + 1) ^ (col & 7)) * 4;
  const int srow = (w << 3) + (lane >> 3);  // w<2: adjacency row 0..15
  const int lch = lane & 7;                 // logical 4-float chunk
  const int pch = lch ^ (srow & 7);         // swizzled physical chunk (adj)

  f32x4 acc00 = {0.f, 0.f, 0.f, 0.f}, acc01 = acc00, acc10 = acc00, acc11 = acc00;
  f32x4 accs0 = acc00, accs1 = acc00;
  const f16x8 ones = {(_Float16)1, (_Float16)1, (_Float16)1, (_Float16)1,
                      (_Float16)1, (_Float16)1, (_Float16)1, (_Float16)1};
  constexpr int KCL = NN / KCn;
  constexpr int NSTEP = KCL / 32;
  const int jc0 = kc * KCL;

  f32x4 stg = {0.f, 0.f, 0.f, 0.f};
#define STAGE_LOAD(jv)                                                         \
  {                                                                            \
    if (w < 2)                                                                 \
      stg = *(const f32x4*)(adj + (size_t)(i0 + srow) * NN + (jv) + lch * 4);  \
    else if (w == 2)                                                           \
      stg = *(const f32x4*)(a_dstT + (size_t)(lane >> 3) * NN + (jv) + lch * 4); \
  }
#define STAGE_WRITE(nb)                                                        \
  {                                                                            \
    if (w < 2)                                                                 \
      *(f32x4*)&adj_s[nb][srow][pch * 4] = stg;                                \
    else if (w == 2)                                                           \
      *(f32x4*)&adT_s[nb][lane >> 3][lch * 4] = stg;                           \
  }
#define KCOMP(cur, jbv)                                                        \
  {                                                                            \
    const _Float16* bp = hblk + (size_t)((jbv) >> 5) * (F * 32) + kg8;         \
    const f16x8 b00 = *(const f16x8*)(bp + (d0 + col) * 32);                   \
    const f16x8 b01 = *(const f16x8*)(bp + (d0 + 16 + col) * 32);              \
    const f16x8 b10 = *(const f16x8*)(bp + (d0 + 32 + col) * 32);              \
    const f16x8 b11 = *(const f16x8*)(bp + (d0 + 48 + col) * 32);              \
    const f32x4 av0 = *(const f32x4*)&adj_s[cur][col][c0_];                    \
    const f32x4 av1 = *(const f32x4*)&adj_s[cur][col][c1_];                    \
    const f32x4 dv00 = *(const f32x4*)&adT_s[cur][h0][kg8];                    \
    const f32x4 dv01 = *(const f32x4*)&adT_s[cur][h0][kg8 + 4];                \
    const f32x4 dv10 = *(const f32x4*)&adT_s[cur][h1][kg8];                    \
    const f32x4 dv11 = *(const f32x4*)&adT_s[cur][h1][kg8 + 4];                \
    f16x8 a0, a1;                                                              \
    _Pragma("unroll")                                                          \
    for (int e = 0; e < 8; ++e) {                                              \
      const float av = (e < 4) ? av0[e & 3] : av1[e & 3];                      \
      const float dv0 = (e < 4) ? dv00[e & 3] : dv01[e & 3];                   \
      const float dv1 = (e < 4) ? dv10[e & 3] : dv11[e & 3];                   \
      float l0 = fmaf(av, ew0, base0 + dv0);                                   \
      l0 = fmaxf(l0, ALPHA * l0);                                              \
      const float w0_ = (av > 0.f) ? __builtin_amdgcn_exp2f(l0) : 0.f;         \
      a0[e] = (_Float16)w0_;                                                   \
      float l1 = fmaf(av, ew1, base1 + dv1);                                   \
      l1 = fmaxf(l1, ALPHA * l1);                                              \
      const float w1_ = (av > 0.f) ? __builtin_amdgcn_exp2f(l1) : 0.f;         \
      a1[e] = (_Float16)w1_;                                                   \
    }                                                                          \
    acc00 = __builtin_amdgcn_mfma_f32_16x16x32_f16(a0, b00, acc00, 0, 0, 0);   \
    acc01 = __builtin_amdgcn_mfma_f32_16x16x32_f16(a0, b01, acc01, 0, 0, 0);   \
    accs0 = __builtin_amdgcn_mfma_f32_16x16x32_f16(a0, ones, accs0, 0, 0, 0);  \
    acc10 = __builtin_amdgcn_mfma_f32_16x16x32_f16(a1, b10, acc10, 0, 0, 0);   \
    acc11 = __builtin_amdgcn_mfma_f32_16x16x32_f16(a1, b11, acc11, 0, 0, 0);   \
    accs1 = __builtin_amdgcn_mfma_f32_16x16x32_f16(a1, ones, accs1, 0, 0, 0);  \
  }

  // prologue: stage step 0
  int jn = jc0;
  STAGE_LOAD(jn);
  STAGE_WRITE(0);
  __syncthreads();
  for (int s = 0; s < NSTEP; ++s) {
    const int cur = s & 1;
    const bool more = (s + 1 < NSTEP);
    if (more) STAGE_LOAD(jn + 32);   // issue early: hides under KCOMP
    KCOMP(cur, jn);
    if (more) STAGE_WRITE(cur ^ 1);  // write late
    __syncthreads();
    jn += 32;
  }
#undef STAGE_LOAD
#undef STAGE_WRITE
#undef KCOMP

  // denominators from ones-MFMA accumulators (rows kg*4+r; take col 0)
  if (col == 0) {
#pragma unroll
    for (int r = 0; r < 4; ++r) {
      swp[((size_t)kc * NN + i0 + kg * 4 + r) * NH + h0] = accs0[r];
      swp[((size_t)kc * NN + i0 + kg * 4 + r) * NH + h1] = accs1[r];
    }
  }
  // stage accs, wave-private transpose, packed f16 stores
#pragma unroll
  for (int r = 0; r < 4; ++r) {
    opart[w][kg * 4 + r][col] = acc00[r];
    opart[w][kg * 4 + r][16 + col] = acc01[r];
    opart[w][kg * 4 + r][32 + col] = acc10[r];
    opart[w][kg * 4 + r][48 + col] = acc11[r];
  }
  const int rr = col, cg = kg;
  f16x8 o0, o1;
#pragma unroll
  for (int q = 0; q < 8; ++q) {
    o0[q] = (_Float16)opart[w][rr][cg * 16 + q];
    o1[q] = (_Float16)opart[w][rr][cg * 16 + 8 + q];
  }
  _Float16* pdst = part + ((size_t)kc * NN + i0 + rr) * F + d0 + cg * 16;
  *(f16x8*)(pdst) = o0;
  *(f16x8*)(pdst + 8) = o1;
}

// ============ Kernel D: reduce partials + normalize + MFMA GEMM + LN + ReLU ====
// Grid 384 (8-row i-tiles): xs rows 8..15 zero-padded (zero A-rows -> zero
// output rows, discarded at store) — 2x resident blocks vs 192 grid.
template <int KCn>
__global__ __launch_bounds__(256) void fuse_ln_mfma(const _Float16* __restrict__ part,
                                                    const float* __restrict__ swp,
                                                    const float* __restrict__ fW,
                                                    const float* __restrict__ fb,
                                                    const float* __restrict__ ln_g,
                                                    const float* __restrict__ ln_b,
                                                    float* __restrict__ out) {
  __shared__ _Float16 xs[16][264];
  __shared__ float ssum[8][NH];
  __shared__ float red[2][4][16];
  const int t = threadIdx.x, w = t >> 6, l = t & 63;
  const int col = l & 15, kg = l >> 4;
  const int i0 = blockIdx.x * 8;
  if (t < 64) {
    const int r = t >> 3, hh = t & 7;
    float s = 0.f;
#pragma unroll
    for (int p = 0; p < KCn; ++p) s += swp[((size_t)p * NN + i0 + r) * NH + hh];
    ssum[r][hh] = s;
  }
  __syncthreads();
  {
    const int c8 = (t & 31) * 8;
    const int hh = (t & 31) >> 2;
    const int rr = t >> 5;  // 0..7
    float sm8[8];
#pragma unroll
    for (int q = 0; q < 8; ++q) sm8[q] = 0.f;
#pragma unroll
    for (int p = 0; p < KCn; ++p) {
      const f16x8 v = *(const f16x8*)(part + ((size_t)p * NN + i0 + rr) * F + c8);
#pragma unroll
      for (int q = 0; q < 8; ++q) sm8[q] += (float)v[q];
    }
    const float inv = 1.f / ssum[rr][hh];
    f16x8 xv, zv;
#pragma unroll
    for (int q = 0; q < 8; ++q) { xv[q] = (_Float16)(sm8[q] * inv); zv[q] = (_Float16)0; }
    *(f16x8*)&xs[rr][c8] = xv;
    *(f16x8*)&xs[rr + 8][c8] = zv;  // zero-pad rows 8..15
  }
  __syncthreads();
  const int cbase = w * 64 + col;
  f32x4 acc0 = {0.f, 0.f, 0.f, 0.f}, acc1 = acc0, acc2 = acc0, acc3 = acc0;
  const float* wr0 = fW + (size_t)cbase * F + kg * 8;
  const float* wr1 = wr0 + (size_t)16 * F;
  const float* wr2 = wr0 + (size_t)32 * F;
  const float* wr3 = wr0 + (size_t)48 * F;
  for (int ks = 0; ks < 8; ++ks) {
    const int k0 = ks * 32;
    const f16x8 af = *(const f16x8*)&xs[col][k0 + kg * 8];
    f16x8 bf0, bf1, bf2, bf3;
#define LDB(dst, ptr)                                                     \
    {                                                                     \
      const f32x4 a = *(const f32x4*)((ptr) + k0);                        \
      const f32x4 b = *(const f32x4*)((ptr) + k0 + 4);                    \
      _Pragma("unroll")                                                   \
      for (int e = 0; e < 4; ++e) { dst[e] = (_Float16)a[e]; dst[4 + e] = (_Float16)b[e]; } \
    }
    LDB(bf0, wr0) LDB(bf1, wr1) LDB(bf2, wr2) LDB(bf3, wr3)
#undef LDB
    acc0 = __builtin_amdgcn_mfma_f32_16x16x32_f16(af, bf0, acc0, 0, 0, 0);
    acc1 = __builtin_amdgcn_mfma_f32_16x16x32_f16(af, bf1, acc1, 0, 0, 0);
    acc2 = __builtin_amdgcn_mfma_f32_16x16x32_f16(af, bf2, acc2, 0, 0, 0);
    acc3 = __builtin_amdgcn_mfma_f32_16x16x32_f16(af, bf3, acc3, 0, 0, 0);
  }
  const float fb0 = fb[cbase], fb1 = fb[cbase + 16], fb2 = fb[cbase + 32], fb3 = fb[cbase + 48];
#pragma unroll
  for (int r = 0; r < 4; ++r) {
    acc0[r] += fb0; acc1[r] += fb1; acc2[r] += fb2; acc3[r] += fb3;
  }
  float sm[4], sq[4];
#pragma unroll
  for (int r = 0; r < 4; ++r) {
    sm[r] = acc0[r] + acc1[r] + acc2[r] + acc3[r];
    sq[r] = acc0[r] * acc0[r] + acc1[r] * acc1[r] + acc2[r] * acc2[r] + acc3[r] * acc3[r];
#pragma unroll
    for (int off = 1; off < 16; off <<= 1) {
      sm[r] += __shfl_xor(sm[r], off);
      sq[r] += __shfl_xor(sq[r], off);
    }
  }
  if (col == 0) {
#pragma unroll
    for (int r = 0; r < 4; ++r) {
      red[0][w][kg * 4 + r] = sm[r];
      red[1][w][kg * 4 + r] = sq[r];
    }
  }
  __syncthreads();
  const float g0 = ln_g[cbase], g1 = ln_g[cbase + 16], g2 = ln_g[cbase + 32], g3 = ln_g[cbase + 48];
  const float b0 = ln_b[cbase], b1 = ln_b[cbase + 16], b2 = ln_b[cbase + 32], b3 = ln_b[cbase + 48];
#pragma unroll
  for (int r = 0; r < 4; ++r) {
    const int row = kg * 4 + r;
    if (row < 8) {
      const float S = red[0][0][row] + red[0][1][row] + red[0][2][row] + red[0][3][row];
      const float Q = red[1][0][row] + red[1][1][row] + red[1][2][row] + red[1][3][row];
      const float mu = S * (1.f / F);
      const float rs = rsqrtf(Q * (1.f / F) - mu * mu + LN_EPS);
      float* orow = out + (size_t)(i0 + row) * F;
      orow[cbase] = fmaxf((acc0[r] - mu) * rs * g0 + b0, 0.f);
      orow[cbase + 16] = fmaxf((acc1[r] - mu) * rs * g1 + b1, 0.f);
      orow[cbase + 32] = fmaxf((acc2[r] - mu) * rs * g2 + b2, 0.f);
      orow[cbase + 48] = fmaxf((acc3[r] - mu) * rs * g3 + b3, 0.f);
    }
  }
}

extern "C" void kernel_launch(void* const* d_in, const int* in_sizes, int n_in,
                              void* d_out, int out_size, void* d_ws, size_t ws_size,
                              hipStream_t stream) {
  const float* x = (const float*)d_in[0];
  const float* adj = (const float*)d_in[1];
  const float* W = (const float*)d_in[2];
  const float* attn_src = (const float*)d_in[3];
  const float* attn_dst = (const float*)d_in[4];
  const float* edge_W = (const float*)d_in[5];
  const float* edge_b = (const float*)d_in[6];
  const float* fuse_W = (const float*)d_in[7];
  const float* fuse_b = (const float*)d_in[8];
  const float* ln_g = (const float*)d_in[9];
  const float* ln_b = (const float*)d_in[10];
  float* out = (float*)d_out;

  const int kcn = 8;

  char* p = (char*)d_ws;
  _Float16* hblk = (_Float16*)p;  p += (size_t)NN * F * 2;
  float* a_src = (float*)p;       p += (size_t)NN * NH * 4;
  float* a_dstT = (float*)p;      p += (size_t)NN * NH * 4;
  float* swp = (float*)p;         p += (size_t)kcn * NN * NH * 4;
  _Float16* part = (_Float16*)p;

  gemm_h_mfma<<<384, 256, 0, stream>>>(x, W, attn_src, attn_dst, hblk, a_src, a_dstT);
  gat_mfma<8><<<192 * 8, 256, 0, stream>>>(adj, hblk, a_src, a_dstT, edge_W, edge_b, part, swp);
  fuse_ln_mfma<8><<<NN / 8, 256, 0, stream>>>(part, swp, fuse_W, fuse_b, ln_g, ln_b, out);
}

// Round 22
// 57.363 us; speedup vs baseline: 1.1358x; 1.1189x over previous
//
#include <hip/hip_runtime.h>
#include <hip/hip_fp16.h>

#define NN 3072
#define F 256
#define NH 8
#define ALPHA 0.2f
#define LN_EPS 1e-5f
#define LOG2E 1.44269504f

typedef float f32x4 __attribute__((ext_vector_type(4)));
typedef _Float16 f16x8 __attribute__((ext_vector_type(8)));

// ============ Kernel A: h = x @ W^T via MFMA (f16 in, f32 acc) ============
__global__ __launch_bounds__(256) void gemm_h_mfma(const float* __restrict__ x,
                                                   const float* __restrict__ W,
                                                   const float* __restrict__ asrc_w,
                                                   const float* __restrict__ adst_w,
                                                   _Float16* __restrict__ hblk,
                                                   float* __restrict__ a_src,
                                                   float* __restrict__ a_dstT) {
  __shared__ _Float16 ys[16][136];
  const int t = threadIdx.x, w = t >> 6, l = t & 63;
  const int col = l & 15, kg = l >> 4;
  const int it = blockIdx.x >> 1, half = blockIdx.x & 1;
  const int i0 = it * 16;
  const int cbase = half * 128 + w * 32 + col;  // wave's head = half*4 + w
  f32x4 acc0 = {0.f, 0.f, 0.f, 0.f}, acc1 = acc0;
  const float* xrow = x + (size_t)(i0 + col) * F + kg * 8;
  const float* wr0 = W + (size_t)cbase * F + kg * 8;
  const float* wr1 = wr0 + (size_t)16 * F;
  for (int ks = 0; ks < 8; ++ks) {
    const int k0 = ks * 32;
    f16x8 af, bf0, bf1;
    {
      const f32x4 a = *(const f32x4*)(xrow + k0);
      const f32x4 b = *(const f32x4*)(xrow + k0 + 4);
#pragma unroll
      for (int e = 0; e < 4; ++e) { af[e] = (_Float16)a[e]; af[4 + e] = (_Float16)b[e]; }
    }
#define LDB(dst, ptr)                                                     \
    {                                                                     \
      const f32x4 a = *(const f32x4*)((ptr) + k0);                        \
      const f32x4 b = *(const f32x4*)((ptr) + k0 + 4);                    \
      _Pragma("unroll")                                                   \
      for (int e = 0; e < 4; ++e) { dst[e] = (_Float16)a[e]; dst[4 + e] = (_Float16)b[e]; } \
    }
    LDB(bf0, wr0) LDB(bf1, wr1)
#undef LDB
    acc0 = __builtin_amdgcn_mfma_f32_16x16x32_f16(af, bf0, acc0, 0, 0, 0);
    acc1 = __builtin_amdgcn_mfma_f32_16x16x32_f16(af, bf1, acc1, 0, 0, 0);
  }
  const int hh = half * 4 + w;
  const float ws0 = asrc_w[cbase], ws1 = asrc_w[cbase + 16];
  const float wd0 = adst_w[cbase], wd1 = adst_w[cbase + 16];
#pragma unroll
  for (int r = 0; r < 4; ++r) {
    float p = acc0[r] * ws0 + acc1[r] * ws1;
    float q = acc0[r] * wd0 + acc1[r] * wd1;
#pragma unroll
    for (int off = 1; off < 16; off <<= 1) {
      p += __shfl_xor(p, off);
      q += __shfl_xor(q, off);
    }
    if (col == 0) {
      const int row = i0 + kg * 4 + r;
      a_src[(size_t)row * NH + hh] = p;
      a_dstT[(size_t)hh * NN + row] = q * LOG2E;  // pre-scaled for exp2
    }
  }
#pragma unroll
  for (int r = 0; r < 4; ++r) {
    ys[kg * 4 + r][w * 32 + col] = (_Float16)acc0[r];
    ys[kg * 4 + r][w * 32 + 16 + col] = (_Float16)acc1[r];
  }
  __syncthreads();
  const int dl = t >> 1, jset = (t & 1) * 8;
  const int jb = i0 >> 5, jjb = (i0 & 31) + jset;
  f16x8 hv;
#pragma unroll
  for (int q = 0; q < 8; ++q) hv[q] = ys[jset + q][dl];
  *(f16x8*)(hblk + (size_t)jb * (F * 32) + (half * 128 + dl) * 32 + jjb) = hv;
}

// ============ Kernel C: dense GAT aggregation via MFMA, LDS-staged ============
// EXACT R19 kernel: separate __shared__ staging buffers (alias-analyzable),
// double-buffered cooperative staging, ones-MFMA denominators, HW exp2.
template <int KCn>
__global__ __launch_bounds__(256) void gat_mfma(const float* __restrict__ adj,
                                                const _Float16* __restrict__ hblk,
                                                const float* __restrict__ a_src,
                                                const float* __restrict__ a_dstT,
                                                const float* __restrict__ edge_W,
                                                const float* __restrict__ edge_b,
                                                _Float16* __restrict__ part,
                                                float* __restrict__ swp) {
  __shared__ float opart[4][16][68];
  __shared__ float adj_s[2][16][32];  // [buf][row][j], chunk-swizzled
  __shared__ float adT_s[2][8][32];   // [buf][head][j]
  const int bid = blockIdx.x;
  const int i0 = (bid % 192) * 16;
  const int kc = bid / 192;
  const int t = threadIdx.x, w = t >> 6, lane = t & 63;
  const int col = lane & 15, kg = lane >> 4;
  const int h0 = w * 2, h1 = h0 + 1, d0 = w * 64;
  const float ew0 = edge_W[h0] * LOG2E, ew1 = edge_W[h1] * LOG2E;
  const float base0 = (a_src[(size_t)(i0 + col) * NH + h0] + edge_b[h0]) * LOG2E;
  const float base1 = (a_src[(size_t)(i0 + col) * NH + h1] + edge_b[h1]) * LOG2E;
  const int kg8 = kg * 8;
  const int c0_ = ((kg * 2) ^ (col & 7)) * 4;
  const int c1_ = ((kg * 2 + 1) ^ (col & 7)) * 4;
  const int srow = (w << 3) + (lane >> 3);  // w<2: adjacency row 0..15
  const int lch = lane & 7;                 // logical 4-float chunk
  const int pch = lch ^ (srow & 7);         // swizzled physical chunk (adj)

  f32x4 acc00 = {0.f, 0.f, 0.f, 0.f}, acc01 = acc00, acc10 = acc00, acc11 = acc00;
  f32x4 accs0 = acc00, accs1 = acc00;
  const f16x8 ones = {(_Float16)1, (_Float16)1, (_Float16)1, (_Float16)1,
                      (_Float16)1, (_Float16)1, (_Float16)1, (_Float16)1};
  constexpr int KCL = NN / KCn;
  constexpr int NSTEP = KCL / 32;
  const int jc0 = kc * KCL;

  f32x4 stg = {0.f, 0.f, 0.f, 0.f};
#define STAGE_LOAD(jv)                                                         \
  {                                                                            \
    if (w < 2)                                                                 \
      stg = *(const f32x4*)(adj + (size_t)(i0 + srow) * NN + (jv) + lch * 4);  \
    else if (w == 2)                                                           \
      stg = *(const f32x4*)(a_dstT + (size_t)(lane >> 3) * NN + (jv) + lch * 4); \
  }
#define STAGE_WRITE(nb)                                                        \
  {                                                                            \
    if (w < 2)                                                                 \
      *(f32x4*)&adj_s[nb][srow][pch * 4] = stg;                                \
    else if (w == 2)                                                           \
      *(f32x4*)&adT_s[nb][lane >> 3][lch * 4] = stg;                           \
  }
#define KCOMP(cur, jbv)                                                        \
  {                                                                            \
    const _Float16* bp = hblk + (size_t)((jbv) >> 5) * (F * 32) + kg8;         \
    const f16x8 b00 = *(const f16x8*)(bp + (d0 + col) * 32);                   \
    const f16x8 b01 = *(const f16x8*)(bp + (d0 + 16 + col) * 32);              \
    const f16x8 b10 = *(const f16x8*)(bp + (d0 + 32 + col) * 32);              \
    const f16x8 b11 = *(const f16x8*)(bp + (d0 + 48 + col) * 32);              \
    const f32x4 av0 = *(const f32x4*)&adj_s[cur][col][c0_];                    \
    const f32x4 av1 = *(const f32x4*)&adj_s[cur][col][c1_];                    \
    const f32x4 dv00 = *(const f32x4*)&adT_s[cur][h0][kg8];                    \
    const f32x4 dv01 = *(const f32x4*)&adT_s[cur][h0][kg8 + 4];                \
    const f32x4 dv10 = *(const f32x4*)&adT_s[cur][h1][kg8];                    \
    const f32x4 dv11 = *(const f32x4*)&adT_s[cur][h1][kg8 + 4];                \
    f16x8 a0, a1;                                                              \
    _Pragma("unroll")                                                          \
    for (int e = 0; e < 8; ++e) {                                              \
      const float av = (e < 4) ? av0[e & 3] : av1[e & 3];                      \
      const float dv0 = (e < 4) ? dv00[e & 3] : dv01[e & 3];                   \
      const float dv1 = (e < 4) ? dv10[e & 3] : dv11[e & 3];                   \
      float l0 = fmaf(av, ew0, base0 + dv0);                                   \
      l0 = fmaxf(l0, ALPHA * l0);                                              \
      const float w0_ = (av > 0.f) ? __builtin_amdgcn_exp2f(l0) : 0.f;         \
      a0[e] = (_Float16)w0_;                                                   \
      float l1 = fmaf(av, ew1, base1 + dv1);                                   \
      l1 = fmaxf(l1, ALPHA * l1);                                              \
      const float w1_ = (av > 0.f) ? __builtin_amdgcn_exp2f(l1) : 0.f;         \
      a1[e] = (_Float16)w1_;                                                   \
    }                                                                          \
    acc00 = __builtin_amdgcn_mfma_f32_16x16x32_f16(a0, b00, acc00, 0, 0, 0);   \
    acc01 = __builtin_amdgcn_mfma_f32_16x16x32_f16(a0, b01, acc01, 0, 0, 0);   \
    accs0 = __builtin_amdgcn_mfma_f32_16x16x32_f16(a0, ones, accs0, 0, 0, 0);  \
    acc10 = __builtin_amdgcn_mfma_f32_16x16x32_f16(a1, b10, acc10, 0, 0, 0);   \
    acc11 = __builtin_amdgcn_mfma_f32_16x16x32_f16(a1, b11, acc11, 0, 0, 0);   \
    accs1 = __builtin_amdgcn_mfma_f32_16x16x32_f16(a1, ones, accs1, 0, 0, 0);  \
  }

  // prologue: stage step 0
  int jn = jc0;
  STAGE_LOAD(jn);
  STAGE_WRITE(0);
  __syncthreads();
  for (int s = 0; s < NSTEP; ++s) {
    const int cur = s & 1;
    const bool more = (s + 1 < NSTEP);
    if (more) STAGE_LOAD(jn + 32);   // issue early: hides under KCOMP
    KCOMP(cur, jn);
    if (more) STAGE_WRITE(cur ^ 1);  // write late
    __syncthreads();
    jn += 32;
  }
#undef STAGE_LOAD
#undef STAGE_WRITE
#undef KCOMP

  // denominators from ones-MFMA accumulators (rows kg*4+r; take col 0)
  if (col == 0) {
#pragma unroll
    for (int r = 0; r < 4; ++r) {
      swp[((size_t)kc * NN + i0 + kg * 4 + r) * NH + h0] = accs0[r];
      swp[((size_t)kc * NN + i0 + kg * 4 + r) * NH + h1] = accs1[r];
    }
  }
  // stage accs, wave-private transpose, packed f16 stores
#pragma unroll
  for (int r = 0; r < 4; ++r) {
    opart[w][kg * 4 + r][col] = acc00[r];
    opart[w][kg * 4 + r][16 + col] = acc01[r];
    opart[w][kg * 4 + r][32 + col] = acc10[r];
    opart[w][kg * 4 + r][48 + col] = acc11[r];
  }
  const int rr = col, cg = kg;
  f16x8 o0, o1;
#pragma unroll
  for (int q = 0; q < 8; ++q) {
    o0[q] = (_Float16)opart[w][rr][cg * 16 + q];
    o1[q] = (_Float16)opart[w][rr][cg * 16 + 8 + q];
  }
  _Float16* pdst = part + ((size_t)kc * NN + i0 + rr) * F + d0 + cg * 16;
  *(f16x8*)(pdst) = o0;
  *(f16x8*)(pdst + 8) = o1;
}

// ============ Kernel D: reduce partials + normalize + MFMA GEMM + LN + ReLU ====
// EXACT R19 version: 16-row i-tiles, grid 192.
template <int KCn>
__global__ __launch_bounds__(256) void fuse_ln_mfma(const _Float16* __restrict__ part,
                                                    const float* __restrict__ swp,
                                                    const float* __restrict__ fW,
                                                    const float* __restrict__ fb,
                                                    const float* __restrict__ ln_g,
                                                    const float* __restrict__ ln_b,
                                                    float* __restrict__ out) {
  __shared__ _Float16 xs[16][264];
  __shared__ float ssum[16][NH];
  __shared__ float red[2][4][16];
  const int t = threadIdx.x, w = t >> 6, l = t & 63;
  const int col = l & 15, kg = l >> 4;
  const int i0 = blockIdx.x * 16;
  if (t < 128) {
    const int r = t >> 3, hh = t & 7;
    float s = 0.f;
#pragma unroll
    for (int p = 0; p < KCn; ++p) s += swp[((size_t)p * NN + i0 + r) * NH + hh];
    ssum[r][hh] = s;
  }
  __syncthreads();
  {
    const int c8 = (t & 31) * 8;
    const int hh = (t & 31) >> 2;
#pragma unroll
    for (int rp = 0; rp < 2; ++rp) {
      const int rr = (t >> 5) + rp * 8;
      float sm8[8];
#pragma unroll
      for (int q = 0; q < 8; ++q) sm8[q] = 0.f;
#pragma unroll
      for (int p = 0; p < KCn; ++p) {
        const f16x8 v = *(const f16x8*)(part + ((size_t)p * NN + i0 + rr) * F + c8);
#pragma unroll
        for (int q = 0; q < 8; ++q) sm8[q] += (float)v[q];
      }
      const float inv = 1.f / ssum[rr][hh];
      f16x8 xv;
#pragma unroll
      for (int q = 0; q < 8; ++q) xv[q] = (_Float16)(sm8[q] * inv);
      *(f16x8*)&xs[rr][c8] = xv;
    }
  }
  __syncthreads();
  const int cbase = w * 64 + col;
  f32x4 acc0 = {0.f, 0.f, 0.f, 0.f}, acc1 = acc0, acc2 = acc0, acc3 = acc0;
  const float* wr0 = fW + (size_t)cbase * F + kg * 8;
  const float* wr1 = wr0 + (size_t)16 * F;
  const float* wr2 = wr0 + (size_t)32 * F;
  const float* wr3 = wr0 + (size_t)48 * F;
  for (int ks = 0; ks < 8; ++ks) {
    const int k0 = ks * 32;
    const f16x8 af = *(const f16x8*)&xs[col][k0 + kg * 8];
    f16x8 bf0, bf1, bf2, bf3;
#define LDB(dst, ptr)                                                     \
    {                                                                     \
      const f32x4 a = *(const f32x4*)((ptr) + k0);                        \
      const f32x4 b = *(const f32x4*)((ptr) + k0 + 4);                    \
      _Pragma("unroll")                                                   \
      for (int e = 0; e < 4; ++e) { dst[e] = (_Float16)a[e]; dst[4 + e] = (_Float16)b[e]; } \
    }
    LDB(bf0, wr0) LDB(bf1, wr1) LDB(bf2, wr2) LDB(bf3, wr3)
#undef LDB
    acc0 = __builtin_amdgcn_mfma_f32_16x16x32_f16(af, bf0, acc0, 0, 0, 0);
    acc1 = __builtin_amdgcn_mfma_f32_16x16x32_f16(af, bf1, acc1, 0, 0, 0);
    acc2 = __builtin_amdgcn_mfma_f32_16x16x32_f16(af, bf2, acc2, 0, 0, 0);
    acc3 = __builtin_amdgcn_mfma_f32_16x16x32_f16(af, bf3, acc3, 0, 0, 0);
  }
  const float fb0 = fb[cbase], fb1 = fb[cbase + 16], fb2 = fb[cbase + 32], fb3 = fb[cbase + 48];
#pragma unroll
  for (int r = 0; r < 4; ++r) {
    acc0[r] += fb0; acc1[r] += fb1; acc2[r] += fb2; acc3[r] += fb3;
  }
  float sm[4], sq[4];
#pragma unroll
  for (int r = 0; r < 4; ++r) {
    sm[r] = acc0[r] + acc1[r] + acc2[r] + acc3[r];
    sq[r] = acc0[r] * acc0[r] + acc1[r] * acc1[r] + acc2[r] * acc2[r] + acc3[r] * acc3[r];
#pragma unroll
    for (int off = 1; off < 16; off <<= 1) {
      sm[r] += __shfl_xor(sm[r], off);
      sq[r] += __shfl_xor(sq[r], off);
    }
  }
  if (col == 0) {
#pragma unroll
    for (int r = 0; r < 4; ++r) {
      red[0][w][kg * 4 + r] = sm[r];
      red[1][w][kg * 4 + r] = sq[r];
    }
  }
  __syncthreads();
  const float g0 = ln_g[cbase], g1 = ln_g[cbase + 16], g2 = ln_g[cbase + 32], g3 = ln_g[cbase + 48];
  const float b0 = ln_b[cbase], b1 = ln_b[cbase + 16], b2 = ln_b[cbase + 32], b3 = ln_b[cbase + 48];
#pragma unroll
  for (int r = 0; r < 4; ++r) {
    const int row = kg * 4 + r;
    const float S = red[0][0][row] + red[0][1][row] + red[0][2][row] + red[0][3][row];
    const float Q = red[1][0][row] + red[1][1][row] + red[1][2][row] + red[1][3][row];
    const float mu = S * (1.f / F);
    const float rs = rsqrtf(Q * (1.f / F) - mu * mu + LN_EPS);
    float* orow = out + (size_t)(i0 + row) * F;
    orow[cbase] = fmaxf((acc0[r] - mu) * rs * g0 + b0, 0.f);
    orow[cbase + 16] = fmaxf((acc1[r] - mu) * rs * g1 + b1, 0.f);
    orow[cbase + 32] = fmaxf((acc2[r] - mu) * rs * g2 + b2, 0.f);
    orow[cbase + 48] = fmaxf((acc3[r] - mu) * rs * g3 + b3, 0.f);
  }
}

extern "C" void kernel_launch(void* const* d_in, const int* in_sizes, int n_in,
                              void* d_out, int out_size, void* d_ws, size_t ws_size,
                              hipStream_t stream) {
  const float* x = (const float*)d_in[0];
  const float* adj = (const float*)d_in[1];
  const float* W = (const float*)d_in[2];
  const float* attn_src = (const float*)d_in[3];
  const float* attn_dst = (const float*)d_in[4];
  const float* edge_W = (const float*)d_in[5];
  const float* edge_b = (const float*)d_in[6];
  const float* fuse_W = (const float*)d_in[7];
  const float* fuse_b = (const float*)d_in[8];
  const float* ln_g = (const float*)d_in[9];
  const float* ln_b = (const float*)d_in[10];
  float* out = (float*)d_out;

  const int kcn = 8;

  char* p = (char*)d_ws;
  _Float16* hblk = (_Float16*)p;  p += (size_t)NN * F * 2;
  float* a_src = (float*)p;       p += (size_t)NN * NH * 4;
  float* a_dstT = (float*)p;      p += (size_t)NN * NH * 4;
  float* swp = (float*)p;         p += (size_t)kcn * NN * NH * 4;
  _Float16* part = (_Float16*)p;

  gemm_h_mfma<<<384, 256, 0, stream>>>(x, W, attn_src, attn_dst, hblk, a_src, a_dstT);
  gat_mfma<8><<<192 * 8, 256, 0, stream>>>(adj, hblk, a_src, a_dstT, edge_W, edge_b, part, swp);
  fuse_ln_mfma<8><<<192, 256, 0, stream>>>(part, swp, fuse_W, fuse_b, ln_g, ln_b, out);
}